// Round 1
// 203.739 us; speedup vs baseline: 1.0751x; 1.0751x over previous
//
#include <hip/hip_runtime.h>

// SNN conv layer: 3x3x16->64 conv (SAME) on 512x512 NHWC + old_potentials,
// threshold 1.0 -> (spikes, reset potentials).
// R5: bf16 implicit-GEMM via mfma_f32_16x16x32_bf16 (93.5us kernel).
// R6: swap MFMA M/N roles (A=weights/co, B=pixels). A and B fragments have
//   identical per-lane layouts (lane&15 = M-or-N idx, quad*8+j = k), so the
//   staging and k-pad logic are unchanged; only the mfma argument order and
//   the epilogue indexing change. D layout now: col=lane&15=pixel,
//   row=quad*4+reg = co-within-16 -> each f32x4 acc reg holds 4 CONTIGUOUS
//   co values. Epilogue: 16 dwordx4 oldp loads (batched, all in flight) +
//   32 dwordx4 stores per thread, replacing R5's 192 scalar 4B ops that left
//   the kernel latency-bound (MfmaUtil 2%, VALUBusy 4.4%, 1.98 TB/s).
//   Predict: kernel ~45-55us, ~4 TB/s, vs ~40us write-BW roofline.

#define H 512
#define W 512
#define CI 16
#define CO 64
#define TX 32
#define TY 8
#define XT 34          // staged x extent (TX + halo)
#define YT 10          // staged y extent (TY + halo)
#define PIX_US 24      // ushorts per pixel slot (16 used; 48B stride -> 2-way banks)
#define KS 152         // s_w k-stride in elements (304B -> 12-bank stride)

typedef float v4f __attribute__((ext_vector_type(4)));
typedef float f32x4 __attribute__((ext_vector_type(4)));
typedef short short8 __attribute__((ext_vector_type(8)));
typedef unsigned int uint4v __attribute__((ext_vector_type(4)));

__device__ __forceinline__ unsigned int pack2bf(float f0, float f1) {
    // round-to-nearest-even bf16 truncation of two floats, packed
    unsigned u0 = __builtin_bit_cast(unsigned, f0);
    unsigned u1 = __builtin_bit_cast(unsigned, f1);
    u0 = (u0 + 0x7FFFu + ((u0 >> 16) & 1u)) >> 16;
    u1 = (u1 + 0x7FFFu + ((u1 >> 16) & 1u)) >> 16;
    return u0 | (u1 << 16);
}

__global__ __launch_bounds__(256, 3)
void snn_conv_mfma(const float* __restrict__ in,
                   const float* __restrict__ w,
                   const float* __restrict__ oldp,
                   float* __restrict__ out_spk,
                   float* __restrict__ out_pot)
{
    __shared__ unsigned short s_in[YT * XT * PIX_US];   // 16320 B, [y][x][16 bf16]
    __shared__ unsigned short s_w[CO * KS];             // 19456 B, [n][k] bf16

    const int tid = threadIdx.x;
    const int bx = blockIdx.x & 15;        // 16 tiles in x
    const int by = blockIdx.x >> 4;        // 64 tiles in y
    const int tx0 = bx * TX, ty0 = by * TY;

    // ---- stage weights -> s_w[n][k] bf16 (transposed from w[k][n])
    {
        const int n  = tid & 63;
        const int kq = tid >> 6;                 // 0..3, 36 k-values each
        #pragma unroll
        for (int kk = 0; kk < 18; ++kk) {
            const int k = kq * 36 + kk * 2;
            const float f0 = w[k * CO + n];      // lanes n contiguous -> coalesced
            const float f1 = w[(k + 1) * CO + n];
            *(unsigned int*)&s_w[n * KS + k] = pack2bf(f0, f1);
        }
    }

    // ---- stage input tile bf16, zero halo
    for (int idx = tid; idx < YT * XT; idx += 256) {
        const int ly = idx / XT, lx = idx - ly * XT;
        const int gy = ty0 + ly - 1, gx = tx0 + lx - 1;
        uint4v pk0, pk1;
        if ((unsigned)gy < H && (unsigned)gx < W) {
            const v4f* p = (const v4f*)(in + (gy * W + gx) * CI);
            v4f a = p[0], b = p[1], c = p[2], d = p[3];
            pk0 = (uint4v){pack2bf(a.x, a.y), pack2bf(a.z, a.w),
                           pack2bf(b.x, b.y), pack2bf(b.z, b.w)};
            pk1 = (uint4v){pack2bf(c.x, c.y), pack2bf(c.z, c.w),
                           pack2bf(d.x, d.y), pack2bf(d.z, d.w)};
        } else {
            pk0 = (uint4v)0u;
            pk1 = (uint4v)0u;
        }
        uint4v* dst = (uint4v*)&s_in[idx * PIX_US];   // 48B slot, 16B-aligned
        dst[0] = pk0;
        dst[1] = pk1;
    }
    __syncthreads();

    // ---- wave-level implicit GEMM: wave handles 2 rows x 32 px = 4 N-tiles
    // (pixels), all 64 co as 4 M-tiles (weights).
    const int lane = tid & 63;
    const int wv   = tid >> 6;       // wave 0..3 -> rows 2wv, 2wv+1
    const int r    = lane & 15;      // n-within-N-tile (pixel) / m-within-M-tile (co)
    const int quad = lane >> 4;      // 0..3
    const int half = quad & 1;       // ci-half for pixel fragment
    const int tsel = quad >> 1;      // tap parity within K-step

    f32x4 acc[4][4] = {};            // [mt=pixel tile][nt=co tile]

    int abase[4];
    #pragma unroll
    for (int mt = 0; mt < 4; ++mt) {
        const int rl = 2 * wv + (mt >> 1);          // local pixel row
        const int xl = (mt & 1) * 16 + r;           // local pixel x
        abase[mt] = (rl * XT + xl) * PIX_US + half * 8;
    }

    const short8 zero8 = {0, 0, 0, 0, 0, 0, 0, 0};

    #pragma unroll
    for (int ks5 = 0; ks5 < 5; ++ks5) {
        const int t0 = ks5 * 2;
        const int t1 = (ks5 == 4) ? 8 : ks5 * 2 + 1;
        const int off0 = ((t0 / 3) * XT + (t0 % 3)) * PIX_US;  // compile-time
        const int off1 = ((t1 / 3) * XT + (t1 % 3)) * PIX_US;  // compile-time
        const int aoff = tsel ? off1 : off0;
        // weights: lane reads k = koff..koff+7 at row co = nt*16 + r
        const int koff = (ks5 < 4) ? (ks5 * 32 + quad * 8) : (128 + half * 8);

        short8 bf[4];
        #pragma unroll
        for (int nt = 0; nt < 4; ++nt)
            bf[nt] = *(const short8*)&s_w[(nt * 16 + r) * KS + koff];

        short8 af[4];
        #pragma unroll
        for (int mt = 0; mt < 4; ++mt) {
            short8 a = *(const short8*)&s_in[abase[mt] + aoff];
            if (ks5 == 4) a = (quad >= 2) ? zero8 : a;   // zero pad k=144..159
            af[mt] = a;
        }

        // A = weights (M=co), B = pixels (N=pixel): for padded k the B side
        // (pixels) is reg-zeroed, so the replicated weight k-reads contribute 0.
        #pragma unroll
        for (int mt = 0; mt < 4; ++mt)
            #pragma unroll
            for (int nt = 0; nt < 4; ++nt)
                acc[mt][nt] = __builtin_amdgcn_mfma_f32_16x16x32_bf16(
                    bf[nt], af[mt], acc[mt][nt], 0, 0, 0);
    }

    // ---- epilogue: D col=lane&15 (pixel), row=quad*4+reg (co-within-16).
    // Each f32x4 acc reg = 4 contiguous co -> dwordx4 loads/stores.
    // Phase 1: issue all 16 oldp loads (full MLP); phase 2: fuse + store.
    f32x4 oldv[4][4];
    int ebase[4];
    #pragma unroll
    for (int mt = 0; mt < 4; ++mt) {
        const int gy = ty0 + 2 * wv + (mt >> 1);
        const int gx = tx0 + (mt & 1) * 16 + r;
        ebase[mt] = (gy * W + gx) * CO + quad * 4;
        #pragma unroll
        for (int nt = 0; nt < 4; ++nt)
            oldv[mt][nt] = *(const f32x4*)(oldp + ebase[mt] + nt * 16);
    }

    #pragma unroll
    for (int mt = 0; mt < 4; ++mt) {
        #pragma unroll
        for (int nt = 0; nt < 4; ++nt) {
            const int idx = ebase[mt] + nt * 16;
            f32x4 np = acc[mt][nt] + oldv[mt][nt];
            f32x4 spk, pot;
            #pragma unroll
            for (int j = 0; j < 4; ++j) {
                const bool s = np[j] >= 1.0f;
                spk[j] = s ? 1.0f : 0.0f;
                pot[j] = s ? 0.0f : np[j];
            }
            *(f32x4*)(out_spk + idx) = spk;
            *(f32x4*)(out_pot + idx) = pot;
        }
    }
}

extern "C" void kernel_launch(void* const* d_in, const int* in_sizes, int n_in,
                              void* d_out, int out_size, void* d_ws, size_t ws_size,
                              hipStream_t stream) {
    const float* in   = (const float*)d_in[0];     // (1,512,512,16)
    const float* w    = (const float*)d_in[1];     // (3,3,16,64)
    const float* oldp = (const float*)d_in[2];     // (1,512,512,64)
    float* out_spk = (float*)d_out;
    float* out_pot = out_spk + (size_t)H * W * CO;

    const int grid = (W / TX) * (H / TY);          // 1024 blocks x 256 thr
    snn_conv_mfma<<<grid, 256, 0, stream>>>(in, w, oldp, out_spk, out_pot);
}